// Round 10
// baseline (2006.510 us; speedup 1.0000x reference)
//
#include <hip/hip_runtime.h>
#include <hip/hip_bf16.h>
#include <stdint.h>

#define AS1 __attribute__((address_space(1)))
#define AS3 __attribute__((address_space(3)))

typedef __bf16 bf16x8_t __attribute__((ext_vector_type(8)));
typedef __bf16 bf16x4_t __attribute__((ext_vector_type(4)));
typedef float  f32x4_t  __attribute__((ext_vector_type(4)));

constexpr int MD = 8192;     // 4*2048 rows of x
constexpr int ND = 11008;    // weight rows = output cols
constexpr int KD = 4096;

// ---- 8-phase 256^2 kernel geometry ----
constexpr int BM8 = 256, BN8 = 256, BK8 = 64;
constexpr int MT8 = MD / BM8;      // 32
constexpr int NT8 = ND / BN8;      // 43
constexpr int NWG8 = MT8 * NT8;    // 1376 (%8==0 -> bijective XCD swizzle)

// ---- fallback 128^2 kernel geometry ----
constexpr int BM = 128, BN = 128, BK = 32;
constexpr int MT = MD / BM, NT = ND / BN, NWG = MT * NT;
constexpr int KSTEPS = KD / BK;

// ---------------- scale = mean(|W|) + eps (two-stage, deterministic, f64 acc) ----
__global__ void k_abs_partial(const float* __restrict__ w, double* __restrict__ part) {
  __shared__ double sm[256];
  const size_t n4 = (size_t)ND * KD / 4;
  const f32x4_t* w4 = (const f32x4_t*)w;
  double s = 0.0;
  for (size_t i = (size_t)blockIdx.x * 256 + threadIdx.x; i < n4; i += (size_t)gridDim.x * 256) {
    f32x4_t v = __builtin_nontemporal_load(&w4[i]);
    s += (double)fabsf(v[0]) + (double)fabsf(v[1]) + (double)fabsf(v[2]) + (double)fabsf(v[3]);
  }
  sm[threadIdx.x] = s;
  __syncthreads();
  for (int o = 128; o > 0; o >>= 1) {
    if ((int)threadIdx.x < o) sm[threadIdx.x] += sm[threadIdx.x + o];
    __syncthreads();
  }
  if (threadIdx.x == 0) part[blockIdx.x] = sm[0];
}

__global__ void k_abs_final(const double* __restrict__ part, float* __restrict__ scale_out) {
  __shared__ double sm[256];
  double s = 0.0;
  for (int i = threadIdx.x; i < 2048; i += 256) s += part[i];
  sm[threadIdx.x] = s;
  __syncthreads();
  for (int o = 128; o > 0; o >>= 1) {
    if ((int)threadIdx.x < o) sm[threadIdx.x] += sm[threadIdx.x + o];
    __syncthreads();
  }
  if (threadIdx.x == 0) {
    double mean = sm[0] / (double)((size_t)ND * KD);
    scale_out[0] = (float)mean + 1e-5f;
  }
}

// ---------------- prepass: ternary-quantize W -> bf16 {-1,0,1} -------------------
__global__ void k_quant_w(const float* __restrict__ w, const float* __restrict__ scale_p,
                          __bf16* __restrict__ wq) {
  const float s = scale_p[0];
  const size_t n4 = (size_t)ND * KD / 4;
  const f32x4_t* w4 = (const f32x4_t*)w;
  bf16x4_t* q4 = (bf16x4_t*)wq;
  for (size_t i = (size_t)blockIdx.x * 256 + threadIdx.x; i < n4; i += (size_t)gridDim.x * 256) {
    f32x4_t v = __builtin_nontemporal_load(&w4[i]);   // w is dead after this pass
    bf16x4_t h;
#pragma unroll
    for (int j = 0; j < 4; ++j) {
      float q = rintf(v[j] / s);
      q = fminf(1.f, fmaxf(-1.f, q));
      h[j] = (__bf16)q;
    }
    q4[i] = h;   // wq stays cacheable: GEMM reads it next
  }
}

// ---------------- prepass: x fp32 -> bf16 ---------------------------------------
__global__ void k_conv_x(const float* __restrict__ x, __bf16* __restrict__ xb) {
  const size_t n4 = (size_t)MD * KD / 4;
  const f32x4_t* x4 = (const f32x4_t*)x;
  bf16x4_t* o4 = (bf16x4_t*)xb;
  for (size_t i = (size_t)blockIdx.x * 256 + threadIdx.x; i < n4; i += (size_t)gridDim.x * 256) {
    f32x4_t v = __builtin_nontemporal_load(&x4[i]);   // x is dead after this pass
    bf16x4_t h;
#pragma unroll
    for (int j = 0; j < 4; ++j) h[j] = (__bf16)v[j];
    o4[i] = h;   // xb stays cacheable
  }
}

// ================= 8-phase 256x256 GEMM (m201-style template) ====================
// C[M,N] = Xb[M,K] * Wq[N,K]^T * scale. 512 thr = 8 waves (2M x 4N), each wave
// owns 128x64 output. BK=64, 2 K-tiles/iteration, 8 phases. LDS 128 KiB.
// XOR slot-swizzle applied on BOTH sides (rule #21).
//
// ROUND 10: TOP-issued ds_read pipeline with SPLIT fragment arrays (zero extra
// VGPR; register file is at the 2-wave/SIMD boundary: 128 VGPR + 128 AGPR acc).
// Splitting a->a_lo/a_hi, b->b_lo/b_hi makes each refill target dead one phase
// before its shared-array reuse point, so every batch issues at a phase TOP
// (post-barrier, pre-MFMA) and drains under this phase's ~620cy MFMA burst:
//   P8-top: a_lo+b_lo(buf0') 12   [a_lo free after P6, b_lo free after P7]
//   P1-top: b_hi(buf0) 4          [b_hi free after P8]
//   P2-top: a_hi(buf0) 8          [a_hi free after P8]
//   P4-top: a_lo+b_lo(buf1) 12    [a_lo free after P2, b_lo free after P3]
//   P5-top: b_hi(buf1) 4          [b_hi free after P4]
//   P6-top: a_hi(buf1) 8          [a_hi free after P4]
// Counted waits at consumption (in-order lgkm):
//   P1: lgkm(4) drains P8's 12 | P2: lgkm(8) drains b_hi | P3: lgkm(0) drains
//   a_hi | P4: none (all X drained @P3) | P5: lgkm(4) | P6: lgkm(8) | P7:
//   lgkm(0) | P8: none. Max outstanding 16 (1-op issue-cap stall, trivial).
// Sync invariants IDENTICAL to round 9 (passing): stage ring, VMC(2)@P3/P7
// ledger, 2 barriers/phase. Issue points all postdate the buffer-confirming
// barrier (P4-top > P3-bar confirms buf1; P8-top > P7-bar confirms buf0').
// WAR: every LDS region's reads retire (lgkm wait) >=1 barrier before restage.
// Correctness backstop: reads are compiler-visible, so hipcc inserts its own
// waits for true deps; our asm waits only tune drain points.

#define BAR8()    __builtin_amdgcn_s_barrier()
#define LGKMC(N)  asm volatile("s_waitcnt lgkmcnt(" #N ")")
#define VMC(N)    asm volatile("s_waitcnt vmcnt(" #N ")" ::: "memory")
#define SCHB()    __builtin_amdgcn_sched_barrier(0)

#define RD_ALO(BUF)                                                              \
  _Pragma("unroll") for (int mm = 0; mm < 4; ++mm) {                             \
    a_lo[mm][0] = *(const bf16x8_t*)(Asl[BUF] + mm * 1024 + aBase + sw0);        \
    a_lo[mm][1] = *(const bf16x8_t*)(Asl[BUF] + mm * 1024 + aBase + sw1);        \
  }
#define RD_AHI(BUF)                                                              \
  _Pragma("unroll") for (int mm = 0; mm < 4; ++mm) {                             \
    a_hi[mm][0] = *(const bf16x8_t*)(Asl[BUF] + (4 + mm) * 1024 + aBase + sw0);  \
    a_hi[mm][1] = *(const bf16x8_t*)(Asl[BUF] + (4 + mm) * 1024 + aBase + sw1);  \
  }
#define RD_BLO(BUF)                                                              \
  _Pragma("unroll") for (int nn = 0; nn < 2; ++nn) {                             \
    b_lo[nn][0] = *(const bf16x8_t*)(Bsl[BUF] + nn * 1024 + bBase + sw0);        \
    b_lo[nn][1] = *(const bf16x8_t*)(Bsl[BUF] + nn * 1024 + bBase + sw1);        \
  }
#define RD_BHI(BUF)                                                              \
  _Pragma("unroll") for (int nn = 0; nn < 2; ++nn) {                             \
    b_hi[nn][0] = *(const bf16x8_t*)(Bsl[BUF] + (2 + nn) * 1024 + bBase + sw0);  \
    b_hi[nn][1] = *(const bf16x8_t*)(Bsl[BUF] + (2 + nn) * 1024 + bBase + sw1);  \
  }
// Quadrant MFMAs: Q(MH,NH) uses a_(lo|hi) x b_(lo|nn hi) -> acc[MH*4+mm][NH*2+nn]
#define MFMA_QG(AF, BF, MH, NH)                                                  \
  _Pragma("unroll") for (int mm = 0; mm < 4; ++mm)                               \
  _Pragma("unroll") for (int nn = 0; nn < 2; ++nn) {                             \
    f32x4_t& c = acc[(MH) * 4 + mm][(NH) * 2 + nn];                              \
    c = __builtin_amdgcn_mfma_f32_16x16x32_bf16(AF[mm][0], BF[nn][0], c, 0, 0, 0); \
    c = __builtin_amdgcn_mfma_f32_16x16x32_bf16(AF[mm][1], BF[nn][1], c, 0, 0, 0); \
  }

#define DO_ITER(T1, T2, T3, FULL)                                                \
  /* P1: Q00 = a_lo*b_lo (issued P8'-top); top-issue b_hi(buf0) */               \
  STAGE(1, 0, 0, (T1));                                                          \
  BAR8();                                                                        \
  SCHB(); RD_BHI(0); SCHB();                                                     \
  LGKMC(4);                                                                      \
  __builtin_amdgcn_s_setprio(1); MFMA_QG(a_lo, b_lo, 0, 0); __builtin_amdgcn_s_setprio(0); \
  BAR8();                                                                        \
  /* P2: Q01 = a_lo*b_hi; top-issue a_hi(buf0) */                                \
  STAGE(1, 0, 1, (T1));                                                          \
  BAR8();                                                                        \
  SCHB(); RD_AHI(0); SCHB();                                                     \
  LGKMC(8);                                                                      \
  __builtin_amdgcn_s_setprio(1); MFMA_QG(a_lo, b_hi, 0, 1); __builtin_amdgcn_s_setprio(0); \
  BAR8();                                                                        \
  /* P3: Q10 = a_hi*b_lo; VMC(2) confirms ALL of buf1 */                         \
  if (FULL) STAGE(0, 1, 0, (T2));                                                \
  BAR8(); LGKMC(0);                                                              \
  __builtin_amdgcn_s_setprio(1); MFMA_QG(a_hi, b_lo, 1, 0); __builtin_amdgcn_s_setprio(0); \
  if (FULL) { VMC(2); } else { VMC(0); }                                         \
  BAR8();                                                                        \
  /* P4: Q11 = a_hi*b_hi; top-issue a_lo+b_lo(buf1) (post-confirm barrier) */    \
  if (FULL) STAGE(0, 1, 1, (T2));                                                \
  BAR8();                                                                        \
  SCHB(); RD_ALO(1); RD_BLO(1); SCHB();                                          \
  __builtin_amdgcn_s_setprio(1); MFMA_QG(a_hi, b_hi, 1, 1); __builtin_amdgcn_s_setprio(0); \
  BAR8();                                                                        \
  /* P5: Q00 buf1; top-issue b_hi(buf1) */                                       \
  if (FULL) STAGE(0, 0, 0, (T2));                                                \
  BAR8();                                                                        \
  SCHB(); RD_BHI(1); SCHB();                                                     \
  LGKMC(4);                                                                      \
  __builtin_amdgcn_s_setprio(1); MFMA_QG(a_lo, b_lo, 0, 0); __builtin_amdgcn_s_setprio(0); \
  BAR8();                                                                        \
  /* P6: Q01 buf1; top-issue a_hi(buf1) */                                       \
  if (FULL) STAGE(0, 0, 1, (T2));                                                \
  BAR8();                                                                        \
  SCHB(); RD_AHI(1); SCHB();                                                     \
  LGKMC(8);                                                                      \
  __builtin_amdgcn_s_setprio(1); MFMA_QG(a_lo, b_hi, 0, 1); __builtin_amdgcn_s_setprio(0); \
  BAR8();                                                                        \
  /* P7: Q10 buf1; VMC(2) confirms ALL of buf0' */                               \
  if (FULL) STAGE(1, 1, 0, (T3));                                                \
  BAR8(); LGKMC(0);                                                              \
  __builtin_amdgcn_s_setprio(1); MFMA_QG(a_hi, b_lo, 1, 0); __builtin_amdgcn_s_setprio(0); \
  if (FULL) { VMC(2); }                                                          \
  BAR8();                                                                        \
  /* P8: Q11 buf1; top-issue a_lo+b_lo(buf0') for next iter (FULL only) */       \
  if (FULL) STAGE(1, 1, 1, (T3));                                                \
  BAR8();                                                                        \
  if (FULL) { SCHB(); RD_ALO(0); RD_BLO(0); SCHB(); }                            \
  __builtin_amdgcn_s_setprio(1); MFMA_QG(a_hi, b_hi, 1, 1); __builtin_amdgcn_s_setprio(0); \
  BAR8();

__global__ __launch_bounds__(512, 2) void k_gemm8(
    const __bf16* __restrict__ xb, const __bf16* __restrict__ wq,
    const float* __restrict__ scale_p, float* __restrict__ out) {
  __shared__ __bf16 smem[2 * 2 * 2 * 8192];  // 128 KiB

  const int tid  = threadIdx.x;
  const int lane = tid & 63;
  const int wid  = tid >> 6;   // 0..7
  const int wr   = wid >> 2;   // M half (0..1)
  const int wc   = wid & 3;    // N quarter (0..3)
  const int lr   = lane & 15;
  const int kq   = lane >> 4;

  // XCD-chunked linear index, then 2D super-tile raster decode:
  // groups of 8 bn x 32 bm (256 tiles), bn fastest; ragged last group (bn 40-42).
  const int wg = ((int)blockIdx.x & 7) * (NWG8 / 8) + ((int)blockIdx.x >> 3);
  int bm, bn;
  if (wg < 1280) {
    const int g = wg >> 8, r = wg & 255;
    bn = g * 8 + (r & 7);
    bm = r >> 3;
  } else {
    const int r = wg - 1280;
    bn = 40 + r % 3;
    bm = r / 3;
  }

  const float scl = scale_p[0];

  // staging chunks: thread covers chunks tid and tid+512 of each half-tile
  // chunk c: row r = c>>3 (0..127), phys slot p = c&7; source slot = p ^ (r&7)
  const int c0 = tid, c1 = tid + 512;
  const int r0 = c0 >> 3, q0 = (c0 & 7) ^ (r0 & 7);
  const int r1 = c1 >> 3, q1 = (c1 & 7) ^ (r1 & 7);
  const __bf16* aPan = xb + (size_t)bm * BM8 * KD;
  const __bf16* bPan = wq + (size_t)bn * BN8 * KD;

  auto STAGE = [&](int buf, int op, int half, int tile) {
    const __bf16* pan = op ? bPan : aPan;
    const __bf16* s0 = pan + (size_t)(half * 128 + r0) * KD + tile * 64 + q0 * 8;
    const __bf16* s1 = pan + (size_t)(half * 128 + r1) * KD + tile * 64 + q1 * 8;
    __bf16* d = smem + ((buf * 2 + op) * 2 + half) * 8192;
    __builtin_amdgcn_global_load_lds((AS1 const void*)s0, (AS3 void*)(d + c0 * 8), 16, 0, 0);
    __builtin_amdgcn_global_load_lds((AS1 const void*)s1, (AS3 void*)(d + c1 * 8), 16, 0, 0);
  };

  // ds_read addressing: frag (row=R, kslot q') lives at elem R*64 + (q'^(R&7))*8.
  const int sw0 = ((kq)     ^ (lr & 7)) * 8;   // kk=0 slots 0..3
  const int sw1 = ((kq + 4) ^ (lr & 7)) * 8;   // kk=1 slots 4..7
  const int aBase = lr * 64;
  const int bBase = ((wc & 1) * 64 + lr) * 64;
  const int bhalf = wc >> 1;
  const __bf16* Asl[2] = { smem + (0 * 4 + 0 * 2 + wr) * 8192,
                           smem + (1 * 4 + 0 * 2 + wr) * 8192 };
  const __bf16* Bsl[2] = { smem + (0 * 4 + 1 * 2 + bhalf) * 8192,
                           smem + (1 * 4 + 1 * 2 + bhalf) * 8192 };

  bf16x8_t a_lo[4][2], a_hi[4][2], b_lo[2][2], b_hi[2][2];
  f32x4_t acc[8][4] = {};

  // ---- prologue: buf0 <- t0 (A+B, 8 loads), b1.B <- t1 (4 loads).
  // VMC(4): oldest 8 = all of buf0 landed; barrier postdates every wave's VMC;
  // THEN issue the P8-equivalent a_lo+b_lo reads. b1.A staged in P1/P2 of iter 0.
  STAGE(0, 0, 0, 0); STAGE(0, 0, 1, 0);
  STAGE(0, 1, 0, 0); STAGE(0, 1, 1, 0);
  STAGE(1, 1, 0, 1); STAGE(1, 1, 1, 1);
  VMC(4);
  BAR8();
  SCHB(); RD_ALO(0); RD_BLO(0); SCHB();

  // ---- main loop: iterations 0..30 full, 31 peeled (no forward stages) ----
  for (int i = 0; i < 31; ++i) {
    const int t1 = 2 * i + 1, t2 = 2 * i + 2, t3 = 2 * i + 3;
    DO_ITER(t1, t2, t3, 1)
  }
  DO_ITER(63, 0, 0, 0)

  // ---- epilogue: C/D layout col=lane&15, row=(lane>>4)*4+reg ----
  // NONTEMPORAL stores: keep the 360 MB output stream out of L2/L3.
  const size_t row0 = (size_t)bm * 256 + wr * 128 + kq * 4;
  const int col0 = bn * 256 + wc * 64 + lr;
#pragma unroll
  for (int m = 0; m < 8; ++m)
#pragma unroll
    for (int j = 0; j < 4; ++j) {
      float* orow = out + (row0 + m * 16 + j) * (size_t)ND + col0;
#pragma unroll
      for (int n = 0; n < 4; ++n)
        __builtin_nontemporal_store(scl * acc[m][n][j], &orow[n * 16]);
    }
}

// ================= fallback 128^2 GEMM (round-1, fp32 on-the-fly) ================
__global__ void k_gemm_fb(const float* __restrict__ x, const float* __restrict__ w,
                          const float* __restrict__ scale_p, float* __restrict__ out) {
  __shared__ __bf16 As[BM * BK];
  __shared__ __bf16 Bs[BN * BK];

  const int tid  = threadIdx.x;
  const int lane = tid & 63;
  const int wid  = tid >> 6;
  const int wr = wid >> 1, wc = wid & 1;
  const int lr = lane & 15, kq = lane >> 4;

  int wg = ((int)blockIdx.x % 8) * (NWG / 8) + (int)blockIdx.x / 8;
  const int bm = wg % MT;
  const int bn = wg / MT;

  const float scl = scale_p[0];
  const float inv = 1.0f / scl;

  const int c0 = tid, c1 = tid + 256;
  const int r0 = c0 >> 2, kk0 = (c0 & 3) * 8;
  const int r1 = c1 >> 2, kk1 = (c1 & 3) * 8;
  const size_t aBase0 = (size_t)(bm * BM + r0) * KD;
  const size_t aBase1 = (size_t)(bm * BM + r1) * KD;
  const size_t bBase0 = (size_t)(bn * BN + r0) * KD;
  const size_t bBase1 = (size_t)(bn * BN + r1) * KD;

  f32x4_t acc[4][4] = {};

  for (int kt = 0; kt < KSTEPS; ++kt) {
    const int k0 = kt * BK;
    {
      const float* g0 = x + aBase0 + k0 + kk0;
      const float* g1 = x + aBase1 + k0 + kk1;
      f32x4_t v0 = *(const f32x4_t*)g0, v1 = *(const f32x4_t*)(g0 + 4);
      f32x4_t v2 = *(const f32x4_t*)g1, v3 = *(const f32x4_t*)(g1 + 4);
      bf16x8_t h0, h1;
#pragma unroll
      for (int j = 0; j < 4; ++j) {
        h0[j] = (__bf16)v0[j]; h0[j + 4] = (__bf16)v1[j];
        h1[j] = (__bf16)v2[j]; h1[j + 4] = (__bf16)v3[j];
      }
      *(bf16x8_t*)(&As[c0 * 8]) = h0;
      *(bf16x8_t*)(&As[c1 * 8]) = h1;
    }
    {
      const float* g0 = w + bBase0 + k0 + kk0;
      const float* g1 = w + bBase1 + k0 + kk1;
      f32x4_t v0 = *(const f32x4_t*)g0, v1 = *(const f32x4_t*)(g0 + 4);
      f32x4_t v2 = *(const f32x4_t*)g1, v3 = *(const f32x4_t*)(g1 + 4);
      bf16x8_t h0, h1;
#pragma unroll
      for (int j = 0; j < 4; ++j) {
        h0[j]     = (__bf16)fminf(1.f, fmaxf(-1.f, rintf(v0[j] * inv)));
        h0[j + 4] = (__bf16)fminf(1.f, fmaxf(-1.f, rintf(v1[j] * inv)));
        h1[j]     = (__bf16)fminf(1.f, fmaxf(-1.f, rintf(v2[j] * inv)));
        h1[j + 4] = (__bf16)fminf(1.f, fmaxf(-1.f, rintf(v3[j] * inv)));
      }
      *(bf16x8_t*)(&Bs[c0 * 8]) = h0;
      *(bf16x8_t*)(&Bs[c1 * 8]) = h1;
    }
    __syncthreads();
    bf16x8_t a[4], b[4];
#pragma unroll
    for (int m = 0; m < 4; ++m)
      a[m] = *(const bf16x8_t*)(&As[(wr * 64 + m * 16 + lr) * BK + kq * 8]);
#pragma unroll
    for (int n = 0; n < 4; ++n)
      b[n] = *(const bf16x8_t*)(&Bs[(wc * 64 + n * 16 + lr) * BK + kq * 8]);
#pragma unroll
    for (int m = 0; m < 4; ++m)
#pragma unroll
      for (int n = 0; n < 4; ++n)
        acc[m][n] = __builtin_amdgcn_mfma_f32_16x16x32_bf16(a[m], b[n], acc[m][n], 0, 0, 0);
    __syncthreads();
  }

  const size_t row0 = (size_t)bm * BM + wr * 64 + kq * 4;
  const int col0 = bn * BN + wc * 64 + lr;
#pragma unroll
  for (int m = 0; m < 4; ++m)
#pragma unroll
    for (int j = 0; j < 4; ++j) {
      float* orow = out + (row0 + m * 16 + j) * (size_t)ND + col0;
#pragma unroll
      for (int n = 0; n < 4; ++n)
        __builtin_nontemporal_store(scl * acc[m][n][j], &orow[n * 16]);
    }
}

// ---------------- launch --------------------------------------------------------
extern "C" void kernel_launch(void* const* d_in, const int* in_sizes, int n_in,
                              void* d_out, int out_size, void* d_ws, size_t ws_size,
                              hipStream_t stream) {
  (void)in_sizes; (void)n_in; (void)out_size;
  const float* x = (const float*)d_in[0];
  const float* w = (const float*)d_in[1];
  float* out = (float*)d_out;

  char* ws = (char*)d_ws;
  float*  scale_p = (float*)ws;
  double* part    = (double*)(ws + 256);
  __bf16* wq      = (__bf16*)(ws + 32768);
  __bf16* xb      = (__bf16*)(ws + 32768 + (size_t)ND * KD * 2);

  const size_t NEED_AB = 32768 + (size_t)ND * KD * 2 + (size_t)MD * KD * 2;
  const bool pre = ws_size >= NEED_AB;

  k_abs_partial<<<2048, 256, 0, stream>>>(w, part);
  k_abs_final<<<1, 256, 0, stream>>>(part, scale_p);

  if (pre) {
    k_quant_w<<<2048, 256, 0, stream>>>(w, scale_p, wq);
    k_conv_x<<<2048, 256, 0, stream>>>(x, xb);
    k_gemm8<<<NWG8, 512, 0, stream>>>(xb, wq, scale_p, out);
  } else {
    k_gemm_fb<<<NWG, 256, 0, stream>>>(x, w, scale_p, out);
  }
}

// Round 11
// 704.825 us; speedup vs baseline: 2.8468x; 2.8468x over previous
//
#include <hip/hip_runtime.h>
#include <hip/hip_bf16.h>
#include <stdint.h>

#define AS1 __attribute__((address_space(1)))
#define AS3 __attribute__((address_space(3)))

typedef __bf16 bf16x8_t __attribute__((ext_vector_type(8)));
typedef __bf16 bf16x4_t __attribute__((ext_vector_type(4)));
typedef float  f32x4_t  __attribute__((ext_vector_type(4)));

constexpr int MD = 8192;     // 4*2048 rows of x
constexpr int ND = 11008;    // weight rows = output cols
constexpr int KD = 4096;

// ---- 8-phase 256^2 kernel geometry ----
constexpr int BM8 = 256, BN8 = 256, BK8 = 64;
constexpr int MT8 = MD / BM8;      // 32
constexpr int NT8 = ND / BN8;      // 43
constexpr int NWG8 = MT8 * NT8;    // 1376 (%8==0 -> bijective XCD swizzle)

// ---- fallback 128^2 kernel geometry ----
constexpr int BM = 128, BN = 128, BK = 32;
constexpr int MT = MD / BM, NT = ND / BN, NWG = MT * NT;
constexpr int KSTEPS = KD / BK;

// ---------------- scale = mean(|W|) + eps (two-stage, deterministic, f64 acc) ----
__global__ void k_abs_partial(const float* __restrict__ w, double* __restrict__ part) {
  __shared__ double sm[256];
  const size_t n4 = (size_t)ND * KD / 4;
  const f32x4_t* w4 = (const f32x4_t*)w;
  double s = 0.0;
  for (size_t i = (size_t)blockIdx.x * 256 + threadIdx.x; i < n4; i += (size_t)gridDim.x * 256) {
    f32x4_t v = __builtin_nontemporal_load(&w4[i]);
    s += (double)fabsf(v[0]) + (double)fabsf(v[1]) + (double)fabsf(v[2]) + (double)fabsf(v[3]);
  }
  sm[threadIdx.x] = s;
  __syncthreads();
  for (int o = 128; o > 0; o >>= 1) {
    if ((int)threadIdx.x < o) sm[threadIdx.x] += sm[threadIdx.x + o];
    __syncthreads();
  }
  if (threadIdx.x == 0) part[blockIdx.x] = sm[0];
}

__global__ void k_abs_final(const double* __restrict__ part, float* __restrict__ scale_out) {
  __shared__ double sm[256];
  double s = 0.0;
  for (int i = threadIdx.x; i < 2048; i += 256) s += part[i];
  sm[threadIdx.x] = s;
  __syncthreads();
  for (int o = 128; o > 0; o >>= 1) {
    if ((int)threadIdx.x < o) sm[threadIdx.x] += sm[threadIdx.x + o];
    __syncthreads();
  }
  if (threadIdx.x == 0) {
    double mean = sm[0] / (double)((size_t)ND * KD);
    scale_out[0] = (float)mean + 1e-5f;
  }
}

// -------- merged prepass: W -> ternary bf16 AND x -> bf16 in one dispatch --------
__global__ void k_prep(const float* __restrict__ w, const float* __restrict__ x,
                       const float* __restrict__ scale_p,
                       __bf16* __restrict__ wq, __bf16* __restrict__ xb) {
  const float s = scale_p[0];
  const size_t nW = (size_t)ND * KD / 4;           // 11,272,192 chunks
  const size_t nT = nW + (size_t)MD * KD / 4;      // + 8,388,608
  const f32x4_t* w4 = (const f32x4_t*)w;
  const f32x4_t* x4 = (const f32x4_t*)x;
  bf16x4_t* q4 = (bf16x4_t*)wq;
  bf16x4_t* o4 = (bf16x4_t*)xb;
  for (size_t i = (size_t)blockIdx.x * 256 + threadIdx.x; i < nT; i += (size_t)gridDim.x * 256) {
    if (i < nW) {
      f32x4_t v = __builtin_nontemporal_load(&w4[i]);   // w dead after this pass
      bf16x4_t h;
#pragma unroll
      for (int j = 0; j < 4; ++j) {
        float q = rintf(v[j] / s);                      // round-half-even, matches np
        q = fminf(1.f, fmaxf(-1.f, q));
        h[j] = (__bf16)q;
      }
      q4[i] = h;                                        // wq cacheable (GEMM reads next)
    } else {
      const size_t k = i - nW;
      f32x4_t v = __builtin_nontemporal_load(&x4[k]);   // x dead after this pass
      bf16x4_t h;
#pragma unroll
      for (int j = 0; j < 4; ++j) h[j] = (__bf16)v[j];
      o4[k] = h;                                        // xb cacheable
    }
  }
}

// ================= 8-phase 256x256 GEMM (round-9 verbatim: best verified) ========
// C[M,N] = Xb[M,K] * Wq[N,K]^T * scale. 512 thr = 8 waves (2M x 4N), each wave
// owns 128x64 output. BK=64, 2 K-tiles/iteration, 8 phases. LDS 128 KiB.
// XOR slot-swizzle applied on BOTH sides (rule #21).
//
// Liveness-correct ds_read prefetch (round 9): quadrant order Q00,Q01,Q10,Q11
// keeps a_lo live through P2, a_hi through P4, b_lo through P3, b_hi through P4.
// Issue points (bottom-of-phase, dead regs only, SCHB-pinned):
//   P4-bottom: a_lo+b_lo buf1 | P5-bottom: b_hi buf1 | P6-bottom: a_hi buf1
//   P8-bottom: a_lo+b_lo buf0' (FULL) | P1-bottom: b_hi buf0 | P2-bottom: a_hi buf0
// Sync invariant: reads of a freshly staged buffer issue only after a barrier
// that postdates EVERY wave's confirming vmcnt:
//   VMC(2)@P3-bottom confirms ALL buf1; VMC(2)@P7-bottom confirms ALL buf0'.
// Stage ring: P1 b1.A.h0<-T1 | P2 b1.A.h1 | P3 b0.B.h0<-T2 | P4 b0.B.h1
//             P5 b0.A.h0     | P6 b0.A.h1 | P7 b1.B.h0<-T3 | P8 b1.B.h1
// WAR: every LDS region's reads retire (lgkm wait) >=1 barrier before restage.
// Peeled iter: VMC(0)@P3 drains all outstanding; P8-bottom reads skipped.

#define BAR8()    __builtin_amdgcn_s_barrier()
#define LGKMC(N)  asm volatile("s_waitcnt lgkmcnt(" #N ")")
#define VMC(N)    asm volatile("s_waitcnt vmcnt(" #N ")" ::: "memory")
#define SCHB()    __builtin_amdgcn_sched_barrier(0)

#define RD_A(BUF, MOFF)                                                          \
  _Pragma("unroll") for (int mm = 0; mm < 4; ++mm) {                             \
    a[mm][0] = *(const bf16x8_t*)(Asl[BUF] + ((MOFF) + mm) * 1024 + aBase + sw0);\
    a[mm][1] = *(const bf16x8_t*)(Asl[BUF] + ((MOFF) + mm) * 1024 + aBase + sw1);\
  }
#define RD_B(BUF, N0)                                                            \
  _Pragma("unroll") for (int nn = 0; nn < 2; ++nn) {                             \
    b[(N0) + nn][0] = *(const bf16x8_t*)(Bsl[BUF] + ((N0) + nn) * 1024 + bBase + sw0); \
    b[(N0) + nn][1] = *(const bf16x8_t*)(Bsl[BUF] + ((N0) + nn) * 1024 + bBase + sw1); \
  }
#define MFMA_Q(MH, NH)                                                           \
  _Pragma("unroll") for (int mm = 0; mm < 4; ++mm)                               \
  _Pragma("unroll") for (int nn = 0; nn < 2; ++nn) {                             \
    f32x4_t& c = acc[(MH) * 4 + mm][(NH) * 2 + nn];                              \
    c = __builtin_amdgcn_mfma_f32_16x16x32_bf16(a[mm][0], b[(NH) * 2 + nn][0], c, 0, 0, 0); \
    c = __builtin_amdgcn_mfma_f32_16x16x32_bf16(a[mm][1], b[(NH) * 2 + nn][1], c, 0, 0, 0); \
  }

#define DO_ITER(T1, T2, T3, FULL)                                                \
  /* P1: Q(0,0)=a_lo*b_lo buf0 (issued prev P8-bottom) */                        \
  STAGE(1, 0, 0, (T1));                                                          \
  BAR8(); LGKMC(0);                                                              \
  __builtin_amdgcn_s_setprio(1); MFMA_Q(0, 0); __builtin_amdgcn_s_setprio(0);    \
  SCHB(); RD_B(0, 2); SCHB();              /* b_hi buf0 */                       \
  BAR8();                                                                        \
  /* P2: Q(0,1)=a_lo*b_hi */                                                     \
  STAGE(1, 0, 1, (T1));                                                          \
  BAR8(); LGKMC(0);                                                              \
  __builtin_amdgcn_s_setprio(1); MFMA_Q(0, 1); __builtin_amdgcn_s_setprio(0);    \
  SCHB(); RD_A(0, 4); SCHB();              /* a_hi buf0 (a_lo now dead) */       \
  BAR8();                                                                        \
  /* P3: Q(1,0)=a_hi*b_lo; VMC(2) confirms ALL of buf1 */                        \
  if (FULL) STAGE(0, 1, 0, (T2));                                                \
  BAR8(); LGKMC(0);                                                              \
  __builtin_amdgcn_s_setprio(1); MFMA_Q(1, 0); __builtin_amdgcn_s_setprio(0);    \
  if (FULL) { VMC(2); } else { VMC(0); }                                         \
  BAR8();                                                                        \
  /* P4: Q(1,1)=a_hi*b_hi; bottom: a_lo+b_lo buf1 (post-confirm barrier) */      \
  if (FULL) STAGE(0, 1, 1, (T2));                                                \
  BAR8();                                                                        \
  __builtin_amdgcn_s_setprio(1); MFMA_Q(1, 1); __builtin_amdgcn_s_setprio(0);    \
  SCHB(); RD_A(1, 0); RD_B(1, 0); SCHB();                                        \
  BAR8();                                                                        \
  /* P5: Q(0,0) buf1 */                                                          \
  if (FULL) STAGE(0, 0, 0, (T2));                                                \
  BAR8(); LGKMC(0);                                                              \
  __builtin_amdgcn_s_setprio(1); MFMA_Q(0, 0); __builtin_amdgcn_s_setprio(0);    \
  SCHB(); RD_B(1, 2); SCHB();              /* b_hi buf1 */                       \
  BAR8();                                                                        \
  /* P6: Q(0,1) buf1 */                                                          \
  if (FULL) STAGE(0, 0, 1, (T2));                                                \
  BAR8(); LGKMC(0);                                                              \
  __builtin_amdgcn_s_setprio(1); MFMA_Q(0, 1); __builtin_amdgcn_s_setprio(0);    \
  SCHB(); RD_A(1, 4); SCHB();              /* a_hi buf1 */                       \
  BAR8();                                                                        \
  /* P7: Q(1,0) buf1; VMC(2) confirms ALL of buf0' */                            \
  if (FULL) STAGE(1, 1, 0, (T3));                                                \
  BAR8(); LGKMC(0);                                                              \
  __builtin_amdgcn_s_setprio(1); MFMA_Q(1, 0); __builtin_amdgcn_s_setprio(0);    \
  if (FULL) { VMC(2); }                                                          \
  BAR8();                                                                        \
  /* P8: Q(1,1) buf1; bottom: a_lo+b_lo buf0' for next P1 (FULL only) */         \
  if (FULL) STAGE(1, 1, 1, (T3));                                                \
  BAR8();                                                                        \
  __builtin_amdgcn_s_setprio(1); MFMA_Q(1, 1); __builtin_amdgcn_s_setprio(0);    \
  if (FULL) { SCHB(); RD_A(0, 0); RD_B(0, 0); SCHB(); }                          \
  BAR8();

__global__ __launch_bounds__(512, 2) void k_gemm8(
    const __bf16* __restrict__ xb, const __bf16* __restrict__ wq,
    const float* __restrict__ scale_p, float* __restrict__ out) {
  __shared__ __bf16 smem[2 * 2 * 2 * 8192];  // 128 KiB

  const int tid  = threadIdx.x;
  const int lane = tid & 63;
  const int wid  = tid >> 6;   // 0..7
  const int wr   = wid >> 2;   // M half (0..1)
  const int wc   = wid & 3;    // N quarter (0..3)
  const int lr   = lane & 15;
  const int kq   = lane >> 4;

  // XCD-chunked linear index, then 2D super-tile raster decode:
  // groups of 8 bn x 32 bm (256 tiles), bn fastest; ragged last group (bn 40-42).
  const int wg = ((int)blockIdx.x & 7) * (NWG8 / 8) + ((int)blockIdx.x >> 3);
  int bm, bn;
  if (wg < 1280) {
    const int g = wg >> 8, r = wg & 255;
    bn = g * 8 + (r & 7);
    bm = r >> 3;
  } else {
    const int r = wg - 1280;
    bn = 40 + r % 3;
    bm = r / 3;
  }

  const float scl = scale_p[0];

  // staging chunks: thread covers chunks tid and tid+512 of each half-tile
  // chunk c: row r = c>>3 (0..127), phys slot p = c&7; source slot = p ^ (r&7)
  const int c0 = tid, c1 = tid + 512;
  const int r0 = c0 >> 3, q0 = (c0 & 7) ^ (r0 & 7);
  const int r1 = c1 >> 3, q1 = (c1 & 7) ^ (r1 & 7);
  const __bf16* aPan = xb + (size_t)bm * BM8 * KD;
  const __bf16* bPan = wq + (size_t)bn * BN8 * KD;

  auto STAGE = [&](int buf, int op, int half, int tile) {
    const __bf16* pan = op ? bPan : aPan;
    const __bf16* s0 = pan + (size_t)(half * 128 + r0) * KD + tile * 64 + q0 * 8;
    const __bf16* s1 = pan + (size_t)(half * 128 + r1) * KD + tile * 64 + q1 * 8;
    __bf16* d = smem + ((buf * 2 + op) * 2 + half) * 8192;
    __builtin_amdgcn_global_load_lds((AS1 const void*)s0, (AS3 void*)(d + c0 * 8), 16, 0, 0);
    __builtin_amdgcn_global_load_lds((AS1 const void*)s1, (AS3 void*)(d + c1 * 8), 16, 0, 0);
  };

  // ds_read addressing: frag (row=R, kslot q') lives at elem R*64 + (q'^(R&7))*8.
  const int sw0 = ((kq)     ^ (lr & 7)) * 8;   // kk=0 slots 0..3
  const int sw1 = ((kq + 4) ^ (lr & 7)) * 8;   // kk=1 slots 4..7
  const int aBase = lr * 64;
  const int bBase = ((wc & 1) * 64 + lr) * 64;
  const int bhalf = wc >> 1;
  const __bf16* Asl[2] = { smem + (0 * 4 + 0 * 2 + wr) * 8192,
                           smem + (1 * 4 + 0 * 2 + wr) * 8192 };
  const __bf16* Bsl[2] = { smem + (0 * 4 + 1 * 2 + bhalf) * 8192,
                           smem + (1 * 4 + 1 * 2 + bhalf) * 8192 };

  bf16x8_t a[4][2], b[4][2];
  f32x4_t acc[8][4] = {};

  // ---- prologue: buf0 <- t0 (A+B, 8 loads), b1.B <- t1 (4 loads).
  // VMC(4): oldest 8 = all of buf0 landed; barrier postdates every wave's VMC;
  // THEN issue P1's a_lo+b_lo reads. b1.A staged in P1/P2 of iter 0.
  STAGE(0, 0, 0, 0); STAGE(0, 0, 1, 0);
  STAGE(0, 1, 0, 0); STAGE(0, 1, 1, 0);
  STAGE(1, 1, 0, 1); STAGE(1, 1, 1, 1);
  VMC(4);
  BAR8();
  SCHB(); RD_A(0, 0); RD_B(0, 0); SCHB();

  // ---- main loop: iterations 0..30 full, 31 peeled (no forward stages) ----
  for (int i = 0; i < 31; ++i) {
    const int t1 = 2 * i + 1, t2 = 2 * i + 2, t3 = 2 * i + 3;
    DO_ITER(t1, t2, t3, 1)
  }
  DO_ITER(63, 0, 0, 0)

  // ---- epilogue: C/D layout col=lane&15, row=(lane>>4)*4+reg ----
  // NONTEMPORAL stores: keep the 360 MB output stream out of L2/L3.
  const size_t row0 = (size_t)bm * 256 + wr * 128 + kq * 4;
  const int col0 = bn * 256 + wc * 64 + lr;
#pragma unroll
  for (int m = 0; m < 8; ++m)
#pragma unroll
    for (int j = 0; j < 4; ++j) {
      float* orow = out + (row0 + m * 16 + j) * (size_t)ND + col0;
#pragma unroll
      for (int n = 0; n < 4; ++n)
        __builtin_nontemporal_store(scl * acc[m][n][j], &orow[n * 16]);
    }
}

// ================= fallback 128^2 GEMM (round-1, fp32 on-the-fly) ================
__global__ void k_gemm_fb(const float* __restrict__ x, const float* __restrict__ w,
                          const float* __restrict__ scale_p, float* __restrict__ out) {
  __shared__ __bf16 As[BM * BK];
  __shared__ __bf16 Bs[BN * BK];

  const int tid  = threadIdx.x;
  const int lane = tid & 63;
  const int wid  = tid >> 6;
  const int wr = wid >> 1, wc = wid & 1;
  const int lr = lane & 15, kq = lane >> 4;

  int wg = ((int)blockIdx.x % 8) * (NWG / 8) + (int)blockIdx.x / 8;
  const int bm = wg % MT;
  const int bn = wg / MT;

  const float scl = scale_p[0];
  const float inv = 1.0f / scl;

  const int c0 = tid, c1 = tid + 256;
  const int r0 = c0 >> 2, kk0 = (c0 & 3) * 8;
  const int r1 = c1 >> 2, kk1 = (c1 & 3) * 8;
  const size_t aBase0 = (size_t)(bm * BM + r0) * KD;
  const size_t aBase1 = (size_t)(bm * BM + r1) * KD;
  const size_t bBase0 = (size_t)(bn * BN + r0) * KD;
  const size_t bBase1 = (size_t)(bn * BN + r1) * KD;

  f32x4_t acc[4][4] = {};

  for (int kt = 0; kt < KSTEPS; ++kt) {
    const int k0 = kt * BK;
    {
      const float* g0 = x + aBase0 + k0 + kk0;
      const float* g1 = x + aBase1 + k0 + kk1;
      f32x4_t v0 = *(const f32x4_t*)g0, v1 = *(const f32x4_t*)(g0 + 4);
      f32x4_t v2 = *(const f32x4_t*)g1, v3 = *(const f32x4_t*)(g1 + 4);
      bf16x8_t h0, h1;
#pragma unroll
      for (int j = 0; j < 4; ++j) {
        h0[j] = (__bf16)v0[j]; h0[j + 4] = (__bf16)v1[j];
        h1[j] = (__bf16)v2[j]; h1[j + 4] = (__bf16)v3[j];
      }
      *(bf16x8_t*)(&As[c0 * 8]) = h0;
      *(bf16x8_t*)(&As[c1 * 8]) = h1;
    }
    {
      const float* g0 = w + bBase0 + k0 + kk0;
      const float* g1 = w + bBase1 + k0 + kk1;
      f32x4_t v0 = *(const f32x4_t*)g0, v1 = *(const f32x4_t*)(g0 + 4);
      f32x4_t v2 = *(const f32x4_t*)g1, v3 = *(const f32x4_t*)(g1 + 4);
      bf16x8_t h0, h1;
#pragma unroll
      for (int j = 0; j < 4; ++j) {
        h0[j]     = (__bf16)fminf(1.f, fmaxf(-1.f, rintf(v0[j] * inv)));
        h0[j + 4] = (__bf16)fminf(1.f, fmaxf(-1.f, rintf(v1[j] * inv)));
        h1[j]     = (__bf16)fminf(1.f, fmaxf(-1.f, rintf(v2[j] * inv)));
        h1[j + 4] = (__bf16)fminf(1.f, fmaxf(-1.f, rintf(v3[j] * inv)));
      }
      *(bf16x8_t*)(&Bs[c0 * 8]) = h0;
      *(bf16x8_t*)(&Bs[c1 * 8]) = h1;
    }
    __syncthreads();
    bf16x8_t a[4], b[4];
#pragma unroll
    for (int m = 0; m < 4; ++m)
      a[m] = *(const bf16x8_t*)(&As[(wr * 64 + m * 16 + lr) * BK + kq * 8]);
#pragma unroll
    for (int n = 0; n < 4; ++n)
      b[n] = *(const bf16x8_t*)(&Bs[(wc * 64 + n * 16 + lr) * BK + kq * 8]);
#pragma unroll
    for (int m = 0; m < 4; ++m)
#pragma unroll
      for (int n = 0; n < 4; ++n)
        acc[m][n] = __builtin_amdgcn_mfma_f32_16x16x32_bf16(a[m], b[n], acc[m][n], 0, 0, 0);
    __syncthreads();
  }

  const size_t row0 = (size_t)bm * BM + wr * 64 + kq * 4;
  const int col0 = bn * BN + wc * 64 + lr;
#pragma unroll
  for (int m = 0; m < 4; ++m)
#pragma unroll
    for (int j = 0; j < 4; ++j) {
      float* orow = out + (row0 + m * 16 + j) * (size_t)ND + col0;
#pragma unroll
      for (int n = 0; n < 4; ++n)
        __builtin_nontemporal_store(scl * acc[m][n][j], &orow[n * 16]);
    }
}

// ---------------- launch --------------------------------------------------------
extern "C" void kernel_launch(void* const* d_in, const int* in_sizes, int n_in,
                              void* d_out, int out_size, void* d_ws, size_t ws_size,
                              hipStream_t stream) {
  (void)in_sizes; (void)n_in; (void)out_size;
  const float* x = (const float*)d_in[0];
  const float* w = (const float*)d_in[1];
  float* out = (float*)d_out;

  char* ws = (char*)d_ws;
  float*  scale_p = (float*)ws;
  double* part    = (double*)(ws + 256);
  __bf16* wq      = (__bf16*)(ws + 32768);
  __bf16* xb      = (__bf16*)(ws + 32768 + (size_t)ND * KD * 2);

  const size_t NEED_AB = 32768 + (size_t)ND * KD * 2 + (size_t)MD * KD * 2;
  const bool pre = ws_size >= NEED_AB;

  k_abs_partial<<<2048, 256, 0, stream>>>(w, part);
  k_abs_final<<<1, 256, 0, stream>>>(part, scale_p);

  if (pre) {
    k_prep<<<2048, 256, 0, stream>>>(w, x, scale_p, wq, xb);
    k_gemm8<<<NWG8, 512, 0, stream>>>(xb, wq, scale_p, out);
  } else {
    k_gemm_fb<<<NWG, 256, 0, stream>>>(x, w, scale_p, out);
  }
}

// Round 12
// 684.826 us; speedup vs baseline: 2.9300x; 1.0292x over previous
//
#include <hip/hip_runtime.h>
#include <hip/hip_bf16.h>
#include <stdint.h>

#define AS1 __attribute__((address_space(1)))
#define AS3 __attribute__((address_space(3)))

typedef __bf16 bf16x8_t __attribute__((ext_vector_type(8)));
typedef __bf16 bf16x4_t __attribute__((ext_vector_type(4)));
typedef float  f32x4_t  __attribute__((ext_vector_type(4)));

constexpr int MD = 8192;     // 4*2048 rows of x
constexpr int ND = 11008;    // weight rows = output cols
constexpr int KD = 4096;

// ---- 8-phase 256^2 kernel geometry ----
constexpr int BM8 = 256, BN8 = 256, BK8 = 64;
constexpr int MT8 = MD / BM8;      // 32
constexpr int NT8 = ND / BN8;      // 43
constexpr int NWG8 = MT8 * NT8;    // 1376 (%8==0 -> bijective XCD swizzle)

// ---- fallback 128^2 kernel geometry ----
constexpr int BM = 128, BN = 128, BK = 32;
constexpr int MT = MD / BM, NT = ND / BN, NWG = MT * NT;
constexpr int KSTEPS = KD / BK;

// ---------------- scale = mean(|W|) + eps (two-stage, deterministic, f64 acc) ----
__global__ void k_abs_partial(const float* __restrict__ w, double* __restrict__ part) {
  __shared__ double sm[256];
  const size_t n4 = (size_t)ND * KD / 4;
  const f32x4_t* w4 = (const f32x4_t*)w;
  double s = 0.0;
  for (size_t i = (size_t)blockIdx.x * 256 + threadIdx.x; i < n4; i += (size_t)gridDim.x * 256) {
    f32x4_t v = __builtin_nontemporal_load(&w4[i]);
    s += (double)fabsf(v[0]) + (double)fabsf(v[1]) + (double)fabsf(v[2]) + (double)fabsf(v[3]);
  }
  sm[threadIdx.x] = s;
  __syncthreads();
  for (int o = 128; o > 0; o >>= 1) {
    if ((int)threadIdx.x < o) sm[threadIdx.x] += sm[threadIdx.x + o];
    __syncthreads();
  }
  if (threadIdx.x == 0) part[blockIdx.x] = sm[0];
}

__global__ void k_abs_final(const double* __restrict__ part, float* __restrict__ scale_out) {
  __shared__ double sm[256];
  double s = 0.0;
  for (int i = threadIdx.x; i < 2048; i += 256) s += part[i];
  sm[threadIdx.x] = s;
  __syncthreads();
  for (int o = 128; o > 0; o >>= 1) {
    if ((int)threadIdx.x < o) sm[threadIdx.x] += sm[threadIdx.x + o];
    __syncthreads();
  }
  if (threadIdx.x == 0) {
    double mean = sm[0] / (double)((size_t)ND * KD);
    scale_out[0] = (float)mean + 1e-5f;
  }
}

// -------- merged prepass: W -> ternary bf16 AND x -> bf16 in one dispatch --------
__global__ void k_prep(const float* __restrict__ w, const float* __restrict__ x,
                       const float* __restrict__ scale_p,
                       __bf16* __restrict__ wq, __bf16* __restrict__ xb) {
  const float s = scale_p[0];
  const size_t nW = (size_t)ND * KD / 4;
  const size_t nT = nW + (size_t)MD * KD / 4;
  const f32x4_t* w4 = (const f32x4_t*)w;
  const f32x4_t* x4 = (const f32x4_t*)x;
  bf16x4_t* q4 = (bf16x4_t*)wq;
  bf16x4_t* o4 = (bf16x4_t*)xb;
  for (size_t i = (size_t)blockIdx.x * 256 + threadIdx.x; i < nT; i += (size_t)gridDim.x * 256) {
    if (i < nW) {
      f32x4_t v = __builtin_nontemporal_load(&w4[i]);
      bf16x4_t h;
#pragma unroll
      for (int j = 0; j < 4; ++j) {
        float q = rintf(v[j] / s);
        q = fminf(1.f, fmaxf(-1.f, q));
        h[j] = (__bf16)q;
      }
      q4[i] = h;
    } else {
      const size_t k = i - nW;
      f32x4_t v = __builtin_nontemporal_load(&x4[k]);
      bf16x4_t h;
#pragma unroll
      for (int j = 0; j < 4; ++j) h[j] = (__bf16)v[j];
      o4[k] = h;
    }
  }
}

// ================= 8-phase 256x256 GEMM =========================================
// ROUND 12 CHANGE: SINGLE barrier per phase (mid-phase barrier removed; 16/iter
// instead of 32). Correctness audit vs round-9 ring:
//  (a) MFMA inputs: own-wave regs gated by own-wave lgkmcnt -> no cross-wave dep.
//  (b) Stage@P vs in-flight reads issued in P-1/P: all pairs disjoint by ring
//      design (checked exhaustively: P1 st b1.A.h0 vs P8'rd buf0 / P1rd buf0.B;
//      P2 st b1.A.h1 vs P1rd buf0.B / P2rd buf0.A; P3 st b0.B.h0 vs P2rd buf0.A;
//      P4 st b0.B.h1 vs P4rd buf1; P5 st b0.A.h0 vs P4rd buf1 / P5rd buf1.B;
//      P6 st b0.A.h1 vs P5rd buf1.B / P6rd buf1.A; P7 st b1.B.h0 vs P6rd buf1.A;
//      P8 st b1.B.h1 vs P8rd buf0). Barrier rendezvous bounds skew to 1 phase.
//  (c) Staging-confirm (RAW): VMC(2)@P3/P7-bottom precede the END-of-phase
//      barrier; dependent reads are in later phases. Unchanged.
//  (d) WAR: reads of R retire at a lgkm wait inside their phase; all waves pass
//      it before any wave exits that phase's end barrier; restage is >=1 phase
//      later. Peeled iter: VMC(0)@P3 drains all before P4-bottom buf1 reads.
// Everything else byte-identical to round 11 (round-9 GEMM, best verified).

#define BAR8()    __builtin_amdgcn_s_barrier()
#define LGKMC(N)  asm volatile("s_waitcnt lgkmcnt(" #N ")")
#define VMC(N)    asm volatile("s_waitcnt vmcnt(" #N ")" ::: "memory")
#define SCHB()    __builtin_amdgcn_sched_barrier(0)

#define RD_A(BUF, MOFF)                                                          \
  _Pragma("unroll") for (int mm = 0; mm < 4; ++mm) {                             \
    a[mm][0] = *(const bf16x8_t*)(Asl[BUF] + ((MOFF) + mm) * 1024 + aBase + sw0);\
    a[mm][1] = *(const bf16x8_t*)(Asl[BUF] + ((MOFF) + mm) * 1024 + aBase + sw1);\
  }
#define RD_B(BUF, N0)                                                            \
  _Pragma("unroll") for (int nn = 0; nn < 2; ++nn) {                             \
    b[(N0) + nn][0] = *(const bf16x8_t*)(Bsl[BUF] + ((N0) + nn) * 1024 + bBase + sw0); \
    b[(N0) + nn][1] = *(const bf16x8_t*)(Bsl[BUF] + ((N0) + nn) * 1024 + bBase + sw1); \
  }
#define MFMA_Q(MH, NH)                                                           \
  _Pragma("unroll") for (int mm = 0; mm < 4; ++mm)                               \
  _Pragma("unroll") for (int nn = 0; nn < 2; ++nn) {                             \
    f32x4_t& c = acc[(MH) * 4 + mm][(NH) * 2 + nn];                              \
    c = __builtin_amdgcn_mfma_f32_16x16x32_bf16(a[mm][0], b[(NH) * 2 + nn][0], c, 0, 0, 0); \
    c = __builtin_amdgcn_mfma_f32_16x16x32_bf16(a[mm][1], b[(NH) * 2 + nn][1], c, 0, 0, 0); \
  }

#define DO_ITER(T1, T2, T3, FULL)                                                \
  /* P1: Q(0,0)=a_lo*b_lo buf0 (issued prev P8-bottom) */                        \
  STAGE(1, 0, 0, (T1));                                                          \
  LGKMC(0);                                                                      \
  __builtin_amdgcn_s_setprio(1); MFMA_Q(0, 0); __builtin_amdgcn_s_setprio(0);    \
  SCHB(); RD_B(0, 2); SCHB();              /* b_hi buf0 */                       \
  BAR8();                                                                        \
  /* P2: Q(0,1)=a_lo*b_hi */                                                     \
  STAGE(1, 0, 1, (T1));                                                          \
  LGKMC(0);                                                                      \
  __builtin_amdgcn_s_setprio(1); MFMA_Q(0, 1); __builtin_amdgcn_s_setprio(0);    \
  SCHB(); RD_A(0, 4); SCHB();              /* a_hi buf0 (a_lo now dead) */       \
  BAR8();                                                                        \
  /* P3: Q(1,0)=a_hi*b_lo; VMC(2) confirms ALL of buf1 */                        \
  if (FULL) STAGE(0, 1, 0, (T2));                                                \
  LGKMC(0);                                                                      \
  __builtin_amdgcn_s_setprio(1); MFMA_Q(1, 0); __builtin_amdgcn_s_setprio(0);    \
  if (FULL) { VMC(2); } else { VMC(0); }                                         \
  BAR8();                                                                        \
  /* P4: Q(1,1)=a_hi*b_hi; bottom: a_lo+b_lo buf1 (post-confirm barrier) */      \
  if (FULL) STAGE(0, 1, 1, (T2));                                                \
  LGKMC(0);                                                                      \
  __builtin_amdgcn_s_setprio(1); MFMA_Q(1, 1); __builtin_amdgcn_s_setprio(0);    \
  SCHB(); RD_A(1, 0); RD_B(1, 0); SCHB();                                        \
  BAR8();                                                                        \
  /* P5: Q(0,0) buf1 */                                                          \
  if (FULL) STAGE(0, 0, 0, (T2));                                                \
  LGKMC(0);                                                                      \
  __builtin_amdgcn_s_setprio(1); MFMA_Q(0, 0); __builtin_amdgcn_s_setprio(0);    \
  SCHB(); RD_B(1, 2); SCHB();              /* b_hi buf1 */                       \
  BAR8();                                                                        \
  /* P6: Q(0,1) buf1 */                                                          \
  if (FULL) STAGE(0, 0, 1, (T2));                                                \
  LGKMC(0);                                                                      \
  __builtin_amdgcn_s_setprio(1); MFMA_Q(0, 1); __builtin_amdgcn_s_setprio(0);    \
  SCHB(); RD_A(1, 4); SCHB();              /* a_hi buf1 */                       \
  BAR8();                                                                        \
  /* P7: Q(1,0) buf1; VMC(2) confirms ALL of buf0' */                            \
  if (FULL) STAGE(1, 1, 0, (T3));                                                \
  LGKMC(0);                                                                      \
  __builtin_amdgcn_s_setprio(1); MFMA_Q(1, 0); __builtin_amdgcn_s_setprio(0);    \
  if (FULL) { VMC(2); }                                                          \
  BAR8();                                                                        \
  /* P8: Q(1,1) buf1; bottom: a_lo+b_lo buf0' for next P1 (FULL only) */         \
  if (FULL) STAGE(1, 1, 1, (T3));                                                \
  LGKMC(0);                                                                      \
  __builtin_amdgcn_s_setprio(1); MFMA_Q(1, 1); __builtin_amdgcn_s_setprio(0);    \
  if (FULL) { SCHB(); RD_A(0, 0); RD_B(0, 0); SCHB(); }                          \
  BAR8();

__global__ __launch_bounds__(512, 2) void k_gemm8(
    const __bf16* __restrict__ xb, const __bf16* __restrict__ wq,
    const float* __restrict__ scale_p, float* __restrict__ out) {
  __shared__ __bf16 smem[2 * 2 * 2 * 8192];  // 128 KiB

  const int tid  = threadIdx.x;
  const int lane = tid & 63;
  const int wid  = tid >> 6;   // 0..7
  const int wr   = wid >> 2;   // M half (0..1)
  const int wc   = wid & 3;    // N quarter (0..3)
  const int lr   = lane & 15;
  const int kq   = lane >> 4;

  // XCD-chunked linear index, then 2D super-tile raster decode:
  // groups of 8 bn x 32 bm (256 tiles), bn fastest; ragged last group (bn 40-42).
  const int wg = ((int)blockIdx.x & 7) * (NWG8 / 8) + ((int)blockIdx.x >> 3);
  int bm, bn;
  if (wg < 1280) {
    const int g = wg >> 8, r = wg & 255;
    bn = g * 8 + (r & 7);
    bm = r >> 3;
  } else {
    const int r = wg - 1280;
    bn = 40 + r % 3;
    bm = r / 3;
  }

  const float scl = scale_p[0];

  // staging chunks: thread covers chunks tid and tid+512 of each half-tile
  // chunk c: row r = c>>3 (0..127), phys slot p = c&7; source slot = p ^ (r&7)
  const int c0 = tid, c1 = tid + 512;
  const int r0 = c0 >> 3, q0 = (c0 & 7) ^ (r0 & 7);
  const int r1 = c1 >> 3, q1 = (c1 & 7) ^ (r1 & 7);
  const __bf16* aPan = xb + (size_t)bm * BM8 * KD;
  const __bf16* bPan = wq + (size_t)bn * BN8 * KD;

  auto STAGE = [&](int buf, int op, int half, int tile) {
    const __bf16* pan = op ? bPan : aPan;
    const __bf16* s0 = pan + (size_t)(half * 128 + r0) * KD + tile * 64 + q0 * 8;
    const __bf16* s1 = pan + (size_t)(half * 128 + r1) * KD + tile * 64 + q1 * 8;
    __bf16* d = smem + ((buf * 2 + op) * 2 + half) * 8192;
    __builtin_amdgcn_global_load_lds((AS1 const void*)s0, (AS3 void*)(d + c0 * 8), 16, 0, 0);
    __builtin_amdgcn_global_load_lds((AS1 const void*)s1, (AS3 void*)(d + c1 * 8), 16, 0, 0);
  };

  // ds_read addressing: frag (row=R, kslot q') lives at elem R*64 + (q'^(R&7))*8.
  const int sw0 = ((kq)     ^ (lr & 7)) * 8;   // kk=0 slots 0..3
  const int sw1 = ((kq + 4) ^ (lr & 7)) * 8;   // kk=1 slots 4..7
  const int aBase = lr * 64;
  const int bBase = ((wc & 1) * 64 + lr) * 64;
  const int bhalf = wc >> 1;
  const __bf16* Asl[2] = { smem + (0 * 4 + 0 * 2 + wr) * 8192,
                           smem + (1 * 4 + 0 * 2 + wr) * 8192 };
  const __bf16* Bsl[2] = { smem + (0 * 4 + 1 * 2 + bhalf) * 8192,
                           smem + (1 * 4 + 1 * 2 + bhalf) * 8192 };

  bf16x8_t a[4][2], b[4][2];
  f32x4_t acc[8][4] = {};

  // ---- prologue: buf0 <- t0 (A+B, 8 loads), b1.B <- t1 (4 loads).
  // VMC(4): oldest 8 = all of buf0 landed; barrier postdates every wave's VMC;
  // THEN issue P1's a_lo+b_lo reads. b1.A staged in P1/P2 of iter 0.
  STAGE(0, 0, 0, 0); STAGE(0, 0, 1, 0);
  STAGE(0, 1, 0, 0); STAGE(0, 1, 1, 0);
  STAGE(1, 1, 0, 1); STAGE(1, 1, 1, 1);
  VMC(4);
  BAR8();
  SCHB(); RD_A(0, 0); RD_B(0, 0); SCHB();

  // ---- main loop: iterations 0..30 full, 31 peeled (no forward stages) ----
  for (int i = 0; i < 31; ++i) {
    const int t1 = 2 * i + 1, t2 = 2 * i + 2, t3 = 2 * i + 3;
    DO_ITER(t1, t2, t3, 1)
  }
  DO_ITER(63, 0, 0, 0)

  // ---- epilogue: C/D layout col=lane&15, row=(lane>>4)*4+reg ----
  // NONTEMPORAL stores: keep the 360 MB output stream out of L2/L3.
  const size_t row0 = (size_t)bm * 256 + wr * 128 + kq * 4;
  const int col0 = bn * 256 + wc * 64 + lr;
#pragma unroll
  for (int m = 0; m < 8; ++m)
#pragma unroll
    for (int j = 0; j < 4; ++j) {
      float* orow = out + (row0 + m * 16 + j) * (size_t)ND + col0;
#pragma unroll
      for (int n = 0; n < 4; ++n)
        __builtin_nontemporal_store(scl * acc[m][n][j], &orow[n * 16]);
    }
}

// ================= fallback 128^2 GEMM (round-1, fp32 on-the-fly) ================
__global__ void k_gemm_fb(const float* __restrict__ x, const float* __restrict__ w,
                          const float* __restrict__ scale_p, float* __restrict__ out) {
  __shared__ __bf16 As[BM * BK];
  __shared__ __bf16 Bs[BN * BK];

  const int tid  = threadIdx.x;
  const int lane = tid & 63;
  const int wid  = tid >> 6;
  const int wr = wid >> 1, wc = wid & 1;
  const int lr = lane & 15, kq = lane >> 4;

  int wg = ((int)blockIdx.x % 8) * (NWG / 8) + (int)blockIdx.x / 8;
  const int bm = wg % MT;
  const int bn = wg / MT;

  const float scl = scale_p[0];
  const float inv = 1.0f / scl;

  const int c0 = tid, c1 = tid + 256;
  const int r0 = c0 >> 2, kk0 = (c0 & 3) * 8;
  const int r1 = c1 >> 2, kk1 = (c1 & 3) * 8;
  const size_t aBase0 = (size_t)(bm * BM + r0) * KD;
  const size_t aBase1 = (size_t)(bm * BM + r1) * KD;
  const size_t bBase0 = (size_t)(bn * BN + r0) * KD;
  const size_t bBase1 = (size_t)(bn * BN + r1) * KD;

  f32x4_t acc[4][4] = {};

  for (int kt = 0; kt < KSTEPS; ++kt) {
    const int k0 = kt * BK;
    {
      const float* g0 = x + aBase0 + k0 + kk0;
      const float* g1 = x + aBase1 + k0 + kk1;
      f32x4_t v0 = *(const f32x4_t*)g0, v1 = *(const f32x4_t*)(g0 + 4);
      f32x4_t v2 = *(const f32x4_t*)g1, v3 = *(const f32x4_t*)(g1 + 4);
      bf16x8_t h0, h1;
#pragma unroll
      for (int j = 0; j < 4; ++j) {
        h0[j] = (__bf16)v0[j]; h0[j + 4] = (__bf16)v1[j];
        h1[j] = (__bf16)v2[j]; h1[j + 4] = (__bf16)v3[j];
      }
      *(bf16x8_t*)(&As[c0 * 8]) = h0;
      *(bf16x8_t*)(&As[c1 * 8]) = h1;
    }
    {
      const float* g0 = w + bBase0 + k0 + kk0;
      const float* g1 = w + bBase1 + k0 + kk1;
      f32x4_t v0 = *(const f32x4_t*)g0, v1 = *(const f32x4_t*)(g0 + 4);
      f32x4_t v2 = *(const f32x4_t*)g1, v3 = *(const f32x4_t*)(g1 + 4);
      bf16x8_t h0, h1;
#pragma unroll
      for (int j = 0; j < 4; ++j) {
        h0[j]     = (__bf16)fminf(1.f, fmaxf(-1.f, rintf(v0[j] * inv)));
        h0[j + 4] = (__bf16)fminf(1.f, fmaxf(-1.f, rintf(v1[j] * inv)));
        h1[j]     = (__bf16)fminf(1.f, fmaxf(-1.f, rintf(v2[j] * inv)));
        h1[j + 4] = (__bf16)fminf(1.f, fmaxf(-1.f, rintf(v3[j] * inv)));
      }
      *(bf16x8_t*)(&Bs[c0 * 8]) = h0;
      *(bf16x8_t*)(&Bs[c1 * 8]) = h1;
    }
    __syncthreads();
    bf16x8_t a[4], b[4];
#pragma unroll
    for (int m = 0; m < 4; ++m)
      a[m] = *(const bf16x8_t*)(&As[(wr * 64 + m * 16 + lr) * BK + kq * 8]);
#pragma unroll
    for (int n = 0; n < 4; ++n)
      b[n] = *(const bf16x8_t*)(&Bs[(wc * 64 + n * 16 + lr) * BK + kq * 8]);
#pragma unroll
    for (int m = 0; m < 4; ++m)
#pragma unroll
      for (int n = 0; n < 4; ++n)
        acc[m][n] = __builtin_amdgcn_mfma_f32_16x16x32_bf16(a[m], b[n], acc[m][n], 0, 0, 0);
    __syncthreads();
  }

  const size_t row0 = (size_t)bm * BM + wr * 64 + kq * 4;
  const int col0 = bn * BN + wc * 64 + lr;
#pragma unroll
  for (int m = 0; m < 4; ++m)
#pragma unroll
    for (int j = 0; j < 4; ++j) {
      float* orow = out + (row0 + m * 16 + j) * (size_t)ND + col0;
#pragma unroll
      for (int n = 0; n < 4; ++n)
        __builtin_nontemporal_store(scl * acc[m][n][j], &orow[n * 16]);
    }
}

// ---------------- launch --------------------------------------------------------
extern "C" void kernel_launch(void* const* d_in, const int* in_sizes, int n_in,
                              void* d_out, int out_size, void* d_ws, size_t ws_size,
                              hipStream_t stream) {
  (void)in_sizes; (void)n_in; (void)out_size;
  const float* x = (const float*)d_in[0];
  const float* w = (const float*)d_in[1];
  float* out = (float*)d_out;

  char* ws = (char*)d_ws;
  float*  scale_p = (float*)ws;
  double* part    = (double*)(ws + 256);
  __bf16* wq      = (__bf16*)(ws + 32768);
  __bf16* xb      = (__bf16*)(ws + 32768 + (size_t)ND * KD * 2);

  const size_t NEED_AB = 32768 + (size_t)ND * KD * 2 + (size_t)MD * KD * 2;
  const bool pre = ws_size >= NEED_AB;

  k_abs_partial<<<2048, 256, 0, stream>>>(w, part);
  k_abs_final<<<1, 256, 0, stream>>>(part, scale_p);

  if (pre) {
    k_prep<<<2048, 256, 0, stream>>>(w, x, scale_p, wq, xb);
    k_gemm8<<<NWG8, 512, 0, stream>>>(xb, wq, scale_p, out);
  } else {
    k_gemm_fb<<<NWG, 256, 0, stream>>>(x, w, scale_p, out);
  }
}

// Round 13
// 657.880 us; speedup vs baseline: 3.0500x; 1.0410x over previous
//
#include <hip/hip_runtime.h>
#include <hip/hip_bf16.h>
#include <stdint.h>

#define AS1 __attribute__((address_space(1)))
#define AS3 __attribute__((address_space(3)))

typedef __bf16 bf16x8_t __attribute__((ext_vector_type(8)));
typedef __bf16 bf16x4_t __attribute__((ext_vector_type(4)));
typedef float  f32x4_t  __attribute__((ext_vector_type(4)));

constexpr int MD = 8192;     // 4*2048 rows of x
constexpr int ND = 11008;    // weight rows = output cols
constexpr int KD = 4096;

// ---- 8-phase 256^2 kernel geometry ----
constexpr int BM8 = 256, BN8 = 256, BK8 = 64;
constexpr int MT8 = MD / BM8;      // 32
constexpr int NT8 = ND / BN8;      // 43
constexpr int NWG8 = MT8 * NT8;    // 1376 (%8==0 -> bijective XCD swizzle)

// ---- fallback 128^2 kernel geometry ----
constexpr int BM = 128, BN = 128, BK = 32;
constexpr int MT = MD / BM, NT = ND / BN, NWG = MT * NT;
constexpr int KSTEPS = KD / BK;

// ---------------- scale = mean(|W|) + eps (two-stage, deterministic, f64 acc) ----
__global__ void k_abs_partial(const float* __restrict__ w, double* __restrict__ part) {
  __shared__ double sm[256];
  const size_t n4 = (size_t)ND * KD / 4;
  const f32x4_t* w4 = (const f32x4_t*)w;
  double s = 0.0;
  for (size_t i = (size_t)blockIdx.x * 256 + threadIdx.x; i < n4; i += (size_t)gridDim.x * 256) {
    f32x4_t v = __builtin_nontemporal_load(&w4[i]);
    s += (double)fabsf(v[0]) + (double)fabsf(v[1]) + (double)fabsf(v[2]) + (double)fabsf(v[3]);
  }
  sm[threadIdx.x] = s;
  __syncthreads();
  for (int o = 128; o > 0; o >>= 1) {
    if ((int)threadIdx.x < o) sm[threadIdx.x] += sm[threadIdx.x + o];
    __syncthreads();
  }
  if (threadIdx.x == 0) part[blockIdx.x] = sm[0];
}

__global__ void k_abs_final(const double* __restrict__ part, float* __restrict__ scale_out) {
  __shared__ double sm[256];
  double s = 0.0;
  for (int i = threadIdx.x; i < 2048; i += 256) s += part[i];
  sm[threadIdx.x] = s;
  __syncthreads();
  for (int o = 128; o > 0; o >>= 1) {
    if ((int)threadIdx.x < o) sm[threadIdx.x] += sm[threadIdx.x + o];
    __syncthreads();
  }
  if (threadIdx.x == 0) {
    double mean = sm[0] / (double)((size_t)ND * KD);
    scale_out[0] = (float)mean + 1e-5f;
  }
}

// -------- merged prepass: W -> ternary bf16 AND x -> bf16 in one dispatch --------
__global__ void k_prep(const float* __restrict__ w, const float* __restrict__ x,
                       const float* __restrict__ scale_p,
                       __bf16* __restrict__ wq, __bf16* __restrict__ xb) {
  const float s = scale_p[0];
  const size_t nW = (size_t)ND * KD / 4;
  const size_t nT = nW + (size_t)MD * KD / 4;
  const f32x4_t* w4 = (const f32x4_t*)w;
  const f32x4_t* x4 = (const f32x4_t*)x;
  bf16x4_t* q4 = (bf16x4_t*)wq;
  bf16x4_t* o4 = (bf16x4_t*)xb;
  for (size_t i = (size_t)blockIdx.x * 256 + threadIdx.x; i < nT; i += (size_t)gridDim.x * 256) {
    if (i < nW) {
      f32x4_t v = __builtin_nontemporal_load(&w4[i]);
      bf16x4_t h;
#pragma unroll
      for (int j = 0; j < 4; ++j) {
        float q = rintf(v[j] / s);
        q = fminf(1.f, fmaxf(-1.f, q));
        h[j] = (__bf16)q;
      }
      q4[i] = h;
    } else {
      const size_t k = i - nW;
      f32x4_t v = __builtin_nontemporal_load(&x4[k]);
      bf16x4_t h;
#pragma unroll
      for (int j = 0; j < 4; ++j) h[j] = (__bf16)v[j];
      o4[k] = h;
    }
  }
}

// ================= 8-phase 256x256 GEMM =========================================
// ROUND 13 CHANGE: barriers only after P2, P3, P6, P7 (4/iter; was 8 in r12).
// Load-bearing set derived by hazard audit:
//  RAW: VMC(2)@P3-bottom + P3-end barrier gate ALL buf1 reads (P4/P5/P6-bottom);
//       VMC(2)@P7-bottom + P7-end barrier gate ALL buf0' reads (P8/P1'/P2').
//  WAR: b0.B restage@P3 <- b_hi(buf0) consumed P2-top lgkm -> P2-end REQUIRED;
//       b1.B restage@P7/P8 <- b_lo/b_hi(buf1) consumed P5/P6-top -> P6-end REQ;
//       b0.A restage@P5/P6 <- a_lo/a_hi(buf0) consumed P1/P3-top -> P3-end covers;
//       b1.A restage@P1/P2 <- a_lo/a_hi(buf1) consumed P5/P7-top -> P7-end covers.
//  Removed barriers (P1,P4,P5,P8-end) create 3-phase skew windows {P4,P5,P6} and
//  {P8,P1,P2}; all cross-wave stage-vs-inflight-read pairs in those windows are
//  region-disjoint (buf0 vs buf1), checked pairwise. VMC/lgkm ledgers are
//  own-wave, skew-independent. Prologue + peeled-iter ledgers unchanged.
// Everything else byte-identical to round 12 (passing, 621us GEMM).

#define BAR8()    __builtin_amdgcn_s_barrier()
#define LGKMC(N)  asm volatile("s_waitcnt lgkmcnt(" #N ")")
#define VMC(N)    asm volatile("s_waitcnt vmcnt(" #N ")" ::: "memory")
#define SCHB()    __builtin_amdgcn_sched_barrier(0)

#define RD_A(BUF, MOFF)                                                          \
  _Pragma("unroll") for (int mm = 0; mm < 4; ++mm) {                             \
    a[mm][0] = *(const bf16x8_t*)(Asl[BUF] + ((MOFF) + mm) * 1024 + aBase + sw0);\
    a[mm][1] = *(const bf16x8_t*)(Asl[BUF] + ((MOFF) + mm) * 1024 + aBase + sw1);\
  }
#define RD_B(BUF, N0)                                                            \
  _Pragma("unroll") for (int nn = 0; nn < 2; ++nn) {                             \
    b[(N0) + nn][0] = *(const bf16x8_t*)(Bsl[BUF] + ((N0) + nn) * 1024 + bBase + sw0); \
    b[(N0) + nn][1] = *(const bf16x8_t*)(Bsl[BUF] + ((N0) + nn) * 1024 + bBase + sw1); \
  }
#define MFMA_Q(MH, NH)                                                           \
  _Pragma("unroll") for (int mm = 0; mm < 4; ++mm)                               \
  _Pragma("unroll") for (int nn = 0; nn < 2; ++nn) {                             \
    f32x4_t& c = acc[(MH) * 4 + mm][(NH) * 2 + nn];                              \
    c = __builtin_amdgcn_mfma_f32_16x16x32_bf16(a[mm][0], b[(NH) * 2 + nn][0], c, 0, 0, 0); \
    c = __builtin_amdgcn_mfma_f32_16x16x32_bf16(a[mm][1], b[(NH) * 2 + nn][1], c, 0, 0, 0); \
  }

#define DO_ITER(T1, T2, T3, FULL)                                                \
  /* P1: Q(0,0)=a_lo*b_lo buf0 (issued prev P8-bottom) */                        \
  STAGE(1, 0, 0, (T1));                                                          \
  LGKMC(0);                                                                      \
  __builtin_amdgcn_s_setprio(1); MFMA_Q(0, 0); __builtin_amdgcn_s_setprio(0);    \
  SCHB(); RD_B(0, 2); SCHB();              /* b_hi buf0 */                       \
  /* P2: Q(0,1)=a_lo*b_hi */                                                     \
  STAGE(1, 0, 1, (T1));                                                          \
  LGKMC(0);                                                                      \
  __builtin_amdgcn_s_setprio(1); MFMA_Q(0, 1); __builtin_amdgcn_s_setprio(0);    \
  SCHB(); RD_A(0, 4); SCHB();              /* a_hi buf0 (a_lo now dead) */       \
  BAR8();                                  /* P2-end: gates b0.B restage @P3 */  \
  /* P3: Q(1,0)=a_hi*b_lo; VMC(2) confirms ALL of buf1 */                        \
  if (FULL) STAGE(0, 1, 0, (T2));                                                \
  LGKMC(0);                                                                      \
  __builtin_amdgcn_s_setprio(1); MFMA_Q(1, 0); __builtin_amdgcn_s_setprio(0);    \
  if (FULL) { VMC(2); } else { VMC(0); }                                         \
  BAR8();                                  /* P3-end: confirm-barrier for buf1 */\
  /* P4: Q(1,1)=a_hi*b_hi; bottom: a_lo+b_lo buf1 */                             \
  if (FULL) STAGE(0, 1, 1, (T2));                                                \
  LGKMC(0);                                                                      \
  __builtin_amdgcn_s_setprio(1); MFMA_Q(1, 1); __builtin_amdgcn_s_setprio(0);    \
  SCHB(); RD_A(1, 0); RD_B(1, 0); SCHB();                                        \
  /* P5: Q(0,0) buf1 */                                                          \
  if (FULL) STAGE(0, 0, 0, (T2));                                                \
  LGKMC(0);                                                                      \
  __builtin_amdgcn_s_setprio(1); MFMA_Q(0, 0); __builtin_amdgcn_s_setprio(0);    \
  SCHB(); RD_B(1, 2); SCHB();              /* b_hi buf1 */                       \
  /* P6: Q(0,1) buf1 */                                                          \
  if (FULL) STAGE(0, 0, 1, (T2));                                                \
  LGKMC(0);                                                                      \
  __builtin_amdgcn_s_setprio(1); MFMA_Q(0, 1); __builtin_amdgcn_s_setprio(0);    \
  SCHB(); RD_A(1, 4); SCHB();              /* a_hi buf1 */                       \
  BAR8();                                  /* P6-end: gates b1.B restage @P7/P8 */\
  /* P7: Q(1,0) buf1; VMC(2) confirms ALL of buf0' */                            \
  if (FULL) STAGE(1, 1, 0, (T3));                                                \
  LGKMC(0);                                                                      \
  __builtin_amdgcn_s_setprio(1); MFMA_Q(1, 0); __builtin_amdgcn_s_setprio(0);    \
  if (FULL) { VMC(2); }                                                          \
  BAR8();                                  /* P7-end: confirm-barrier for buf0' */\
  /* P8: Q(1,1) buf1; bottom: a_lo+b_lo buf0' for next P1 (FULL only) */         \
  if (FULL) STAGE(1, 1, 1, (T3));                                                \
  LGKMC(0);                                                                      \
  __builtin_amdgcn_s_setprio(1); MFMA_Q(1, 1); __builtin_amdgcn_s_setprio(0);    \
  if (FULL) { SCHB(); RD_A(0, 0); RD_B(0, 0); SCHB(); }

__global__ __launch_bounds__(512, 2) void k_gemm8(
    const __bf16* __restrict__ xb, const __bf16* __restrict__ wq,
    const float* __restrict__ scale_p, float* __restrict__ out) {
  __shared__ __bf16 smem[2 * 2 * 2 * 8192];  // 128 KiB

  const int tid  = threadIdx.x;
  const int lane = tid & 63;
  const int wid  = tid >> 6;   // 0..7
  const int wr   = wid >> 2;   // M half (0..1)
  const int wc   = wid & 3;    // N quarter (0..3)
  const int lr   = lane & 15;
  const int kq   = lane >> 4;

  // XCD-chunked linear index, then 2D super-tile raster decode:
  // groups of 8 bn x 32 bm (256 tiles), bn fastest; ragged last group (bn 40-42).
  const int wg = ((int)blockIdx.x & 7) * (NWG8 / 8) + ((int)blockIdx.x >> 3);
  int bm, bn;
  if (wg < 1280) {
    const int g = wg >> 8, r = wg & 255;
    bn = g * 8 + (r & 7);
    bm = r >> 3;
  } else {
    const int r = wg - 1280;
    bn = 40 + r % 3;
    bm = r / 3;
  }

  const float scl = scale_p[0];

  // staging chunks: thread covers chunks tid and tid+512 of each half-tile
  // chunk c: row r = c>>3 (0..127), phys slot p = c&7; source slot = p ^ (r&7)
  const int c0 = tid, c1 = tid + 512;
  const int r0 = c0 >> 3, q0 = (c0 & 7) ^ (r0 & 7);
  const int r1 = c1 >> 3, q1 = (c1 & 7) ^ (r1 & 7);
  const __bf16* aPan = xb + (size_t)bm * BM8 * KD;
  const __bf16* bPan = wq + (size_t)bn * BN8 * KD;

  auto STAGE = [&](int buf, int op, int half, int tile) {
    const __bf16* pan = op ? bPan : aPan;
    const __bf16* s0 = pan + (size_t)(half * 128 + r0) * KD + tile * 64 + q0 * 8;
    const __bf16* s1 = pan + (size_t)(half * 128 + r1) * KD + tile * 64 + q1 * 8;
    __bf16* d = smem + ((buf * 2 + op) * 2 + half) * 8192;
    __builtin_amdgcn_global_load_lds((AS1 const void*)s0, (AS3 void*)(d + c0 * 8), 16, 0, 0);
    __builtin_amdgcn_global_load_lds((AS1 const void*)s1, (AS3 void*)(d + c1 * 8), 16, 0, 0);
  };

  // ds_read addressing: frag (row=R, kslot q') lives at elem R*64 + (q'^(R&7))*8.
  const int sw0 = ((kq)     ^ (lr & 7)) * 8;   // kk=0 slots 0..3
  const int sw1 = ((kq + 4) ^ (lr & 7)) * 8;   // kk=1 slots 4..7
  const int aBase = lr * 64;
  const int bBase = ((wc & 1) * 64 + lr) * 64;
  const int bhalf = wc >> 1;
  const __bf16* Asl[2] = { smem + (0 * 4 + 0 * 2 + wr) * 8192,
                           smem + (1 * 4 + 0 * 2 + wr) * 8192 };
  const __bf16* Bsl[2] = { smem + (0 * 4 + 1 * 2 + bhalf) * 8192,
                           smem + (1 * 4 + 1 * 2 + bhalf) * 8192 };

  bf16x8_t a[4][2], b[4][2];
  f32x4_t acc[8][4] = {};

  // ---- prologue: buf0 <- t0 (A+B, 8 loads), b1.B <- t1 (4 loads).
  // VMC(4): oldest 8 = all of buf0 landed; barrier postdates every wave's VMC;
  // THEN issue P1's a_lo+b_lo reads. b1.A staged in P1/P2 of iter 0.
  STAGE(0, 0, 0, 0); STAGE(0, 0, 1, 0);
  STAGE(0, 1, 0, 0); STAGE(0, 1, 1, 0);
  STAGE(1, 1, 0, 1); STAGE(1, 1, 1, 1);
  VMC(4);
  BAR8();
  SCHB(); RD_A(0, 0); RD_B(0, 0); SCHB();

  // ---- main loop: iterations 0..30 full, 31 peeled (no forward stages) ----
  for (int i = 0; i < 31; ++i) {
    const int t1 = 2 * i + 1, t2 = 2 * i + 2, t3 = 2 * i + 3;
    DO_ITER(t1, t2, t3, 1)
  }
  DO_ITER(63, 0, 0, 0)

  // ---- epilogue: C/D layout col=lane&15, row=(lane>>4)*4+reg ----
  // NONTEMPORAL stores: keep the 360 MB output stream out of L2/L3.
  const size_t row0 = (size_t)bm * 256 + wr * 128 + kq * 4;
  const int col0 = bn * 256 + wc * 64 + lr;
#pragma unroll
  for (int m = 0; m < 8; ++m)
#pragma unroll
    for (int j = 0; j < 4; ++j) {
      float* orow = out + (row0 + m * 16 + j) * (size_t)ND + col0;
#pragma unroll
      for (int n = 0; n < 4; ++n)
        __builtin_nontemporal_store(scl * acc[m][n][j], &orow[n * 16]);
    }
}

// ================= fallback 128^2 GEMM (round-1, fp32 on-the-fly) ================
__global__ void k_gemm_fb(const float* __restrict__ x, const float* __restrict__ w,
                          const float* __restrict__ scale_p, float* __restrict__ out) {
  __shared__ __bf16 As[BM * BK];
  __shared__ __bf16 Bs[BN * BK];

  const int tid  = threadIdx.x;
  const int lane = tid & 63;
  const int wid  = tid >> 6;
  const int wr = wid >> 1, wc = wid & 1;
  const int lr = lane & 15, kq = lane >> 4;

  int wg = ((int)blockIdx.x % 8) * (NWG / 8) + (int)blockIdx.x / 8;
  const int bm = wg % MT;
  const int bn = wg / MT;

  const float scl = scale_p[0];
  const float inv = 1.0f / scl;

  const int c0 = tid, c1 = tid + 256;
  const int r0 = c0 >> 2, kk0 = (c0 & 3) * 8;
  const int r1 = c1 >> 2, kk1 = (c1 & 3) * 8;
  const size_t aBase0 = (size_t)(bm * BM + r0) * KD;
  const size_t aBase1 = (size_t)(bm * BM + r1) * KD;
  const size_t bBase0 = (size_t)(bn * BN + r0) * KD;
  const size_t bBase1 = (size_t)(bn * BN + r1) * KD;

  f32x4_t acc[4][4] = {};

  for (int kt = 0; kt < KSTEPS; ++kt) {
    const int k0 = kt * BK;
    {
      const float* g0 = x + aBase0 + k0 + kk0;
      const float* g1 = x + aBase1 + k0 + kk1;
      f32x4_t v0 = *(const f32x4_t*)g0, v1 = *(const f32x4_t*)(g0 + 4);
      f32x4_t v2 = *(const f32x4_t*)g1, v3 = *(const f32x4_t*)(g1 + 4);
      bf16x8_t h0, h1;
#pragma unroll
      for (int j = 0; j < 4; ++j) {
        h0[j] = (__bf16)v0[j]; h0[j + 4] = (__bf16)v1[j];
        h1[j] = (__bf16)v2[j]; h1[j + 4] = (__bf16)v3[j];
      }
      *(bf16x8_t*)(&As[c0 * 8]) = h0;
      *(bf16x8_t*)(&As[c1 * 8]) = h1;
    }
    {
      const float* g0 = w + bBase0 + k0 + kk0;
      const float* g1 = w + bBase1 + k0 + kk1;
      f32x4_t v0 = *(const f32x4_t*)g0, v1 = *(const f32x4_t*)(g0 + 4);
      f32x4_t v2 = *(const f32x4_t*)g1, v3 = *(const f32x4_t*)(g1 + 4);
      bf16x8_t h0, h1;
#pragma unroll
      for (int j = 0; j < 4; ++j) {
        h0[j]     = (__bf16)fminf(1.f, fmaxf(-1.f, rintf(v0[j] * inv)));
        h0[j + 4] = (__bf16)fminf(1.f, fmaxf(-1.f, rintf(v1[j] * inv)));
        h1[j]     = (__bf16)fminf(1.f, fmaxf(-1.f, rintf(v2[j] * inv)));
        h1[j + 4] = (__bf16)fminf(1.f, fmaxf(-1.f, rintf(v3[j] * inv)));
      }
      *(bf16x8_t*)(&Bs[c0 * 8]) = h0;
      *(bf16x8_t*)(&Bs[c1 * 8]) = h1;
    }
    __syncthreads();
    bf16x8_t a[4], b[4];
#pragma unroll
    for (int m = 0; m < 4; ++m)
      a[m] = *(const bf16x8_t*)(&As[(wr * 64 + m * 16 + lr) * BK + kq * 8]);
#pragma unroll
    for (int n = 0; n < 4; ++n)
      b[n] = *(const bf16x8_t*)(&Bs[(wc * 64 + n * 16 + lr) * BK + kq * 8]);
#pragma unroll
    for (int m = 0; m < 4; ++m)
#pragma unroll
      for (int n = 0; n < 4; ++n)
        acc[m][n] = __builtin_amdgcn_mfma_f32_16x16x32_bf16(a[m], b[n], acc[m][n], 0, 0, 0);
    __syncthreads();
  }

  const size_t row0 = (size_t)bm * BM + wr * 64 + kq * 4;
  const int col0 = bn * BN + wc * 64 + lr;
#pragma unroll
  for (int m = 0; m < 4; ++m)
#pragma unroll
    for (int j = 0; j < 4; ++j) {
      float* orow = out + (row0 + m * 16 + j) * (size_t)ND + col0;
#pragma unroll
      for (int n = 0; n < 4; ++n)
        __builtin_nontemporal_store(scl * acc[m][n][j], &orow[n * 16]);
    }
}

// ---------------- launch --------------------------------------------------------
extern "C" void kernel_launch(void* const* d_in, const int* in_sizes, int n_in,
                              void* d_out, int out_size, void* d_ws, size_t ws_size,
                              hipStream_t stream) {
  (void)in_sizes; (void)n_in; (void)out_size;
  const float* x = (const float*)d_in[0];
  const float* w = (const float*)d_in[1];
  float* out = (float*)d_out;

  char* ws = (char*)d_ws;
  float*  scale_p = (float*)ws;
  double* part    = (double*)(ws + 256);
  __bf16* wq      = (__bf16*)(ws + 32768);
  __bf16* xb      = (__bf16*)(ws + 32768 + (size_t)ND * KD * 2);

  const size_t NEED_AB = 32768 + (size_t)ND * KD * 2 + (size_t)MD * KD * 2;
  const bool pre = ws_size >= NEED_AB;

  k_abs_partial<<<2048, 256, 0, stream>>>(w, part);
  k_abs_final<<<1, 256, 0, stream>>>(part, scale_p);

  if (pre) {
    k_prep<<<2048, 256, 0, stream>>>(w, x, scale_p, wq, xb);
    k_gemm8<<<NWG8, 512, 0, stream>>>(xb, wq, scale_p, out);
  } else {
    k_gemm_fb<<<NWG, 256, 0, stream>>>(x, w, scale_p, out);
  }
}